// Round 8
// baseline (1475.636 us; speedup 1.0000x reference)
//
#include <hip/hip_runtime.h>

#define L_SEQ 2048
#define C_IN  64
#define HH    128
#define NSEQ  32
#define B2    64     // 2*NSEQ sequences (fwd + rev)
#define G3    384    // 3*H
#define T_TILE 128

typedef _Float16 half2_t __attribute__((ext_vector_type(2)));

// keep a value opaque + register-resident (defeats rematerialization)
#define PINU(v) asm volatile("" : "+v"(v))

__device__ __forceinline__ float fdot2u(unsigned int a, unsigned int b, float c) {
    return __builtin_amdgcn_fdot2(__builtin_bit_cast(half2_t, a),
                                  __builtin_bit_cast(half2_t, b), c, false);
}

__device__ __forceinline__ unsigned int pack_h2(float a, float b) {
    half2_t t; t.x = (_Float16)a; t.y = (_Float16)b;
    return __builtin_bit_cast(unsigned int, t);
}

// quad-perm DPP add: reduce across lane^1, pure VALU (no DS pipe)
__device__ __forceinline__ float qadd1(float x) {   // += lane^1
    int t = __builtin_amdgcn_update_dpp(0, __builtin_bit_cast(int, x),
                                        0xB1, 0xF, 0xF, true); // [1,0,3,2]
    return x + __builtin_bit_cast(float, t);
}

__device__ __forceinline__ float fast_sigmoid(float x) {
    float e = __builtin_amdgcn_exp2f(-1.4426950408889634f * x);
    return __builtin_amdgcn_rcpf(1.0f + e);
}

__device__ __forceinline__ float fast_tanh(float x) {
    float a = fabsf(x);
    float e = __builtin_amdgcn_exp2f(-2.8853900817779268f * a); // e^{-2a}
    float r = (1.0f - e) * __builtin_amdgcn_rcpf(1.0f + e);
    return copysignf(r, x);
}

// ---------------------------------------------------------------------------
// Kernel 1: xw[s][tt][j] = bias[j] + sum_c xb[s][t0+tt][c] * W_ih[c][j]
// bias folds b_ih + b_hh for the r,z columns (j<256). x rows are
// block-uniform -> s_load broadcast; branchless row addressing + unroll 4
// keeps 4 independent s_load chains in flight. NO occupancy cap (s_load-
// latency-bound: wants max waves). 384 threads, thread = col j.
// ---------------------------------------------------------------------------
__global__ __launch_bounds__(384)
void xw_kernel(const float* __restrict__ x, const int* __restrict__ lengths,
               const float* __restrict__ W_ih, const float* __restrict__ b_ih,
               const float* __restrict__ b_hh,
               float* __restrict__ xw, int t0, int chunk_steps)
{
    const int tid = threadIdx.x;
    const int tilesPerSeq = chunk_steps / T_TILE;
    const int s    = blockIdx.x / tilesPerSeq;
    const int tile = blockIdx.x % tilesPerSeq;
    const int tbase = t0 + tile * T_TILE;          // global t of row 0

    const bool isFwd = (s < NSEQ);
    const int  len   = isFwd ? L_SEQ : lengths[s - NSEQ];
    const float* __restrict__ xseq = x + (size_t)(s % NSEQ) * L_SEQ * C_IN;

    const int j = tid;
    float w[64];
#pragma unroll
    for (int q = 0; q < 64; ++q) w[q] = W_ih[q * G3 + j];
#pragma unroll
    for (int q = 0; q < 64; ++q) PINU(w[q]);
    const float bias = b_ih[j] + ((j < 256) ? b_hh[j] : 0.f);

    const int tloc = tile * T_TILE;
#pragma unroll 4
    for (int r = 0; r < T_TILE; ++r) {
        const int t = tbase + r;
        const int src = isFwd ? t : (len - 1 - t);      // block-uniform
        float acc = bias;
        if (src >= 0) {                                  // valid (t < len)
            const float* __restrict__ xrow = xseq + (size_t)src * C_IN;
#pragma unroll
            for (int q = 0; q < 64; ++q) acc += xrow[q] * w[q];
        }
        xw[((size_t)s * chunk_steps + (tloc + r)) * G3 + j] = acc;
    }
}

// ---------------------------------------------------------------------------
// Kernel 2: GRU recurrence. 32 blocks x 512 threads = 8 waves: waves 0-3
// run sequence 2b, waves 4-7 run sequence 2b+1. Each SIMD hosts one wave of
// each sequence -> while one stalls (LDS latency, trans ops, barrier), the
// other issues. Per-thread work unchanged: column j = tl>>1, K-half p = tl&1,
// 96 packed f16-pair weight u32s pinned in VGPRs, f16 h double-buffered in
// per-seq LDS, v_dot2_f32_f16 MACs, one DPP qadd per gate, raw s_barrier
// per step drains lgkmcnt only (out-stores + 4-deep xw prefetch in flight).
// ---------------------------------------------------------------------------
__global__ __launch_bounds__(512) __attribute__((amdgpu_waves_per_eu(2, 2)))
void gru_kernel(const float* __restrict__ xw, const float* __restrict__ W_hh,
                const float* __restrict__ b_hh, float* __restrict__ out,
                float* __restrict__ hstate, int t0, int chunk_steps)
{
    __shared__ unsigned int hbufu[2][2][64];   // [seq][buf][u32] (128 f16 each)
    const int tid = threadIdx.x;
    const int q   = tid >> 8;            // which of the block's 2 sequences
    const int tl  = tid & 255;           // thread id within the sequence
    const int s   = blockIdx.x * 2 + q;  // global sequence 0..63
    const int j   = tl >> 1;             // 0..127 output column
    const int p   = tl & 1;              // K half: k in [64p, 64p+64)

    // packed f16-pair weights: W_hh[64p+2q .. +1][col], col in {j,128+j,256+j}
    unsigned int wr[32], wz[32], wn[32];
    const float* Wb = W_hh + (size_t)(64 * p) * G3;
#pragma unroll
    for (int k = 0; k < 32; ++k) {
        wr[k] = pack_h2(Wb[(2*k) * G3 + j],       Wb[(2*k+1) * G3 + j]);
        wz[k] = pack_h2(Wb[(2*k) * G3 + 128 + j], Wb[(2*k+1) * G3 + 128 + j]);
        wn[k] = pack_h2(Wb[(2*k) * G3 + 256 + j], Wb[(2*k+1) * G3 + 256 + j]);
    }
#pragma unroll
    for (int k = 0; k < 32; ++k) { PINU(wr[k]); PINU(wz[k]); PINU(wn[k]); }
    float bn = b_hh[256 + j];
    PINU(bn);

    float hreg = (t0 == 0) ? 0.f : hstate[s * HH + j];   // own column's h (f32)
    if (tl < HH) {
        const float hv = (t0 == 0) ? 0.f : hstate[s * HH + tl];
        ((_Float16*)&hbufu[q][0][0])[tl] = (_Float16)hv;
    }
    __syncthreads();

    const float* xwp = xw + (size_t)s * chunk_steps * G3;
    float cr[4], cz[4], cn[4];
#pragma unroll
    for (int u = 0; u < 4; ++u) {
        const float* qp = xwp + (size_t)u * G3;
        cr[u] = qp[j]; cz[u] = qp[128 + j]; cn[u] = qp[256 + j];
    }

    float* outbase = out + (size_t)(s % NSEQ) * L_SEQ * 256 + ((s < NSEQ) ? 0 : HH);
    int cur = 0;

    for (int t = 0; t < chunk_steps; t += 4) {
        const int tnb = (t + 4 < chunk_steps) ? (t + 4) : t;   // clamp (dead)
        float nr[4], nz[4], nn[4];
#pragma unroll
        for (int u = 0; u < 4; ++u) {
            const float* qp = xwp + (size_t)(tnb + u) * G3;
            nr[u] = qp[j]; nz[u] = qp[128 + j]; nn[u] = qp[256 + j];
        }

#pragma unroll
        for (int u = 0; u < 4; ++u) {
            float ar = 0.f, az = 0.f, an = 0.f;
            const uint4* hb = (const uint4*)&hbufu[q][cur][p * 32];
#pragma unroll
            for (int i = 0; i < 8; ++i) {
                const uint4 hv = hb[i];
                ar = fdot2u(hv.x, wr[4*i+0], ar); ar = fdot2u(hv.y, wr[4*i+1], ar);
                ar = fdot2u(hv.z, wr[4*i+2], ar); ar = fdot2u(hv.w, wr[4*i+3], ar);
                az = fdot2u(hv.x, wz[4*i+0], az); az = fdot2u(hv.y, wz[4*i+1], az);
                az = fdot2u(hv.z, wz[4*i+2], az); az = fdot2u(hv.w, wz[4*i+3], az);
                an = fdot2u(hv.x, wn[4*i+0], an); an = fdot2u(hv.y, wn[4*i+1], an);
                an = fdot2u(hv.z, wn[4*i+2], an); an = fdot2u(hv.w, wn[4*i+3], an);
            }
            // combine the 2 K-halves in-register (single DPP add per gate)
            ar = qadd1(ar);
            az = qadd1(az);
            an = qadd1(an);

            // biases b_hh_r, b_hh_z are folded into cr/cz by xw_kernel
            const float r = fast_sigmoid(cr[u] + ar);
            const float z = fast_sigmoid(cz[u] + az);
            const float n = fast_tanh(cn[u] + r * (an + bn));
            const float hnew = z * (hreg - n) + n;
            hreg = hnew;

            if (p == 0) {
                ((_Float16*)&hbufu[q][cur ^ 1][0])[j] = (_Float16)hnew;
                outbase[(size_t)(t0 + t + u) * 256 + j] = hnew;
            }
            // raw barrier: drain LDS only (h exchange); vmcnt stays in flight
            asm volatile("s_waitcnt lgkmcnt(0)\n\ts_barrier" ::: "memory");
            cur ^= 1;
        }
#pragma unroll
        for (int u = 0; u < 4; ++u) { cr[u] = nr[u]; cz[u] = nz[u]; cn[u] = nn[u]; }
    }

    if (t0 + chunk_steps < L_SEQ && p == 0) hstate[s * HH + j] = hreg;
}

// ---------------------------------------------------------------------------
extern "C" void kernel_launch(void* const* d_in, const int* in_sizes, int n_in,
                              void* d_out, int out_size, void* d_ws, size_t ws_size,
                              hipStream_t stream) {
    const float* x       = (const float*)d_in[0];
    const int*   lengths = (const int*)  d_in[1];
    const float* W_ih    = (const float*)d_in[2];
    const float* W_hh    = (const float*)d_in[3];
    const float* b_ih    = (const float*)d_in[4];
    const float* b_hh    = (const float*)d_in[5];
    float* out = (float*)d_out;

    // ws layout: [hstate: B2*HH floats][xw chunk buffer: rest]
    float* hstate = (float*)d_ws;
    float* xw     = hstate + B2 * HH;
    const size_t per_step = (size_t)B2 * G3 * sizeof(float);       // 98304 B
    size_t avail = (ws_size > (size_t)B2 * HH * sizeof(float))
                 ? ws_size - (size_t)B2 * HH * sizeof(float) : 0;
    long long csteps = (long long)(avail / per_step);
    int chunk;
    if (csteps >= L_SEQ)       chunk = L_SEQ;                       // single pass
    else if (csteps >= T_TILE) chunk = (int)((csteps / T_TILE) * T_TILE);
    else                       chunk = T_TILE;                      // best effort

    for (int t0 = 0; t0 < L_SEQ; t0 += chunk) {
        const int steps = (L_SEQ - t0 < chunk) ? (L_SEQ - t0) : chunk;
        xw_kernel<<<dim3((steps / T_TILE) * B2), dim3(384), 0, stream>>>(
            x, lengths, W_ih, b_ih, b_hh, xw, t0, steps);
        gru_kernel<<<dim3(B2 / 2), dim3(512), 0, stream>>>(
            xw, W_hh, b_hh, out, hstate, t0, steps);
    }
}

// Round 9
// 1151.490 us; speedup vs baseline: 1.2815x; 1.2815x over previous
//
#include <hip/hip_runtime.h>

#define L_SEQ 2048
#define C_IN  64
#define HH    128
#define NSEQ  32
#define B2    64     // 2*NSEQ sequences (fwd + rev)
#define G3    384    // 3*H
#define RING  16     // LDS xw ring slots (steps)

typedef _Float16 half2_t __attribute__((ext_vector_type(2)));

// keep a value opaque + register-resident (defeats rematerialization)
#define PINU(v) asm volatile("" : "+v"(v))
// per-step barrier: drain LDS only; vmcnt (out-stores, x prefetch) stays in flight
#define STEP_BARRIER() asm volatile("s_waitcnt lgkmcnt(0)\n\ts_barrier" ::: "memory")

__device__ __forceinline__ float fdot2u(unsigned int a, unsigned int b, float c) {
    return __builtin_amdgcn_fdot2(__builtin_bit_cast(half2_t, a),
                                  __builtin_bit_cast(half2_t, b), c, false);
}

__device__ __forceinline__ unsigned int pack_h2(float a, float b) {
    half2_t t; t.x = (_Float16)a; t.y = (_Float16)b;   // RNE rounding
    return __builtin_bit_cast(unsigned int, t);
}

// quad-perm DPP add: reduce across lane^1, pure VALU (no DS pipe)
__device__ __forceinline__ float qadd1(float x) {
    int t = __builtin_amdgcn_update_dpp(0, __builtin_bit_cast(int, x),
                                        0xB1, 0xF, 0xF, true); // [1,0,3,2]
    return x + __builtin_bit_cast(float, t);
}

__device__ __forceinline__ float fast_sigmoid(float x) {
    float e = __builtin_amdgcn_exp2f(-1.4426950408889634f * x);
    return __builtin_amdgcn_rcpf(1.0f + e);
}

__device__ __forceinline__ float fast_tanh(float x) {
    float a = fabsf(x);
    float e = __builtin_amdgcn_exp2f(-2.8853900817779268f * a); // e^{-2a}
    float r = (1.0f - e) * __builtin_amdgcn_rcpf(1.0f + e);
    return copysignf(r, x);
}

// 32 x v_dot2 over one packed-f16 64-elem row held in LDS (broadcast reads)
__device__ __forceinline__ float pdot32(const unsigned int (&w)[32],
                                        const unsigned int* xrow, float acc) {
    const uint4* x4 = (const uint4*)xrow;
#pragma unroll
    for (int i = 0; i < 8; ++i) {
        const uint4 v = x4[i];
        acc = fdot2u(v.x, w[4*i+0], acc);
        acc = fdot2u(v.y, w[4*i+1], acc);
        acc = fdot2u(v.z, w[4*i+2], acc);
        acc = fdot2u(v.w, w[4*i+3], acc);
    }
    return acc;
}

// ---------------------------------------------------------------------------
// Fused BiGRU: 64 blocks (one per sequence), 512 threads = 8 waves.
// Waves 0-3 (consumer): the recurrence — col j = u>>1, K-half p = u&1,
//   96 packed f16 W_hh pairs pinned in VGPRs, h f16 double-buffered in LDS,
//   xw read from the LDS ring (1-step register prefetch).
// Waves 4-7 (producer): x@W_ih computed 6-8 steps ahead into the ring.
//   Each SIMD hosts one consumer + one producer wave: producer issue fills
//   the consumer's serial-latency windows. No global xw buffer at all.
// ---------------------------------------------------------------------------
__global__ __launch_bounds__(512) __attribute__((amdgpu_waves_per_eu(1, 1)))
void bigru_fused(const float* __restrict__ x, const int* __restrict__ lengths,
                 const float* __restrict__ W_ih, const float* __restrict__ W_hh,
                 const float* __restrict__ b_ih, const float* __restrict__ b_hh,
                 float* __restrict__ out)
{
    __shared__ unsigned int hbufu[2][64];        // h as f16 pairs, double-buffered
    __shared__ float        ring[RING][G3];      // xw ring (bias folded)
    __shared__ unsigned int xstage[2][2][32];    // packed x rows, double-buffered

    const int tid = threadIdx.x;
    const int s   = blockIdx.x;
    const bool isFwd = (s < NSEQ);
    const int  len   = isFwd ? L_SEQ : lengths[s - NSEQ];
    const float* __restrict__ xseq = x + (size_t)(s % NSEQ) * L_SEQ * C_IN;

    const bool consumer = (tid < 256);
    const int u = tid & 255;      // role-local thread id
    const int j = u >> 1;         // consumer: output column
    const int p = u & 1;          // consumer: K half

    // weight registers are UNIONED across roles (same virtual regs)
    unsigned int w0[32], w1[32], w2[32];
    float bA = 0.f, bB = 0.f;

    if (consumer) {
        const float* Wb = W_hh + (size_t)(64 * p) * G3;
#pragma unroll
        for (int k = 0; k < 32; ++k) {
            w0[k] = pack_h2(Wb[(2*k) * G3 + j],       Wb[(2*k+1) * G3 + j]);
            w1[k] = pack_h2(Wb[(2*k) * G3 + 128 + j], Wb[(2*k+1) * G3 + 128 + j]);
            w2[k] = pack_h2(Wb[(2*k) * G3 + 256 + j], Wb[(2*k+1) * G3 + 256 + j]);
        }
#pragma unroll
        for (int k = 0; k < 32; ++k) { PINU(w0[k]); PINU(w1[k]); PINU(w2[k]); }
        bA = b_hh[256 + j];                       // b_hh_n (used as r*(an+bA))
        if (tid < 64) hbufu[0][tid] = 0u;         // h0 = 0
    } else {
#pragma unroll
        for (int k = 0; k < 32; ++k)
            w0[k] = pack_h2(W_ih[(2*k) * G3 + u], W_ih[(2*k+1) * G3 + u]);
        bA = b_ih[u] + b_hh[u];                   // r/z cols: fold both biases
        if (u >= 128) {
            const int c1 = 128 + u;               // n-gate cols 256..383
#pragma unroll
            for (int k = 0; k < 32; ++k)
                w1[k] = pack_h2(W_ih[(2*k) * G3 + c1], W_ih[(2*k+1) * G3 + c1]);
            bB = b_ih[c1];
        }
#pragma unroll
        for (int k = 0; k < 32; ++k) { PINU(w0[k]); PINU(w1[k]); }
    }

    float2 xv = make_float2(0.f, 0.f);   // producer: staged x pair (A -> B)

    // ---- prologue: ring rows 0..5 filled; xstage[1] <- rows 6,7 staged ----
    for (int pg = 0; pg < 4; ++pg) {
        if (!consumer && u < 64) {
            const int rowIdx = 2 * pg + (u >= 32 ? 1 : 0);
            const int e = u & 31;
            const int srcL = isFwd ? rowIdx : (len - 1 - rowIdx);
            float2 v = make_float2(0.f, 0.f);
            if (srcL >= 0) v = *(const float2*)&xseq[(size_t)srcL * C_IN + 2*e];
            xstage[pg & 1][(u >= 32) ? 1 : 0][e] = pack_h2(v.x, v.y);
        }
        __syncthreads();
        if (!consumer && pg < 3) {
            const unsigned int* xsA = &xstage[pg & 1][0][0];
            const unsigned int* xsB = &xstage[pg & 1][1][0];
            ring[2*pg][u]     = pdot32(w0, xsA, bA);
            ring[2*pg + 1][u] = pdot32(w0, xsB, bA);
            if (u >= 128) {
                ring[2*pg][128 + u]     = pdot32(w1, xsA, bB);
                ring[2*pg + 1][128 + u] = pdot32(w1, xsB, bB);
            }
        }
        __syncthreads();
    }

    float cr = 0.f, cz = 0.f, cn = 0.f, nr = 0.f, nz = 0.f, nn = 0.f;
    float hreg = 0.f;
    if (consumer) { cr = ring[0][j]; cz = ring[0][128 + j]; cn = ring[0][256 + j]; }

    float* outbase = out + (size_t)(s % NSEQ) * L_SEQ * 256 + (isFwd ? 0 : HH);
    int cur = 0;

    for (int g = 0; g < L_SEQ / 2; ++g) {
        const int tA = 2 * g;
        // ========================= step A (t = 2g) =========================
        if (consumer) {
            const int sln = (tA + 1) & (RING - 1);           // prefetch t+1
            nr = ring[sln][j]; nz = ring[sln][128 + j]; nn = ring[sln][256 + j];
            float ar = 0.f, az = 0.f, an = 0.f;
            const uint4* hb = (const uint4*)&hbufu[cur][p * 32];
#pragma unroll
            for (int i = 0; i < 8; ++i) {
                const uint4 hv = hb[i];
                ar = fdot2u(hv.x, w0[4*i+0], ar); ar = fdot2u(hv.y, w0[4*i+1], ar);
                ar = fdot2u(hv.z, w0[4*i+2], ar); ar = fdot2u(hv.w, w0[4*i+3], ar);
                az = fdot2u(hv.x, w1[4*i+0], az); az = fdot2u(hv.y, w1[4*i+1], az);
                az = fdot2u(hv.z, w1[4*i+2], az); az = fdot2u(hv.w, w1[4*i+3], az);
                an = fdot2u(hv.x, w2[4*i+0], an); an = fdot2u(hv.y, w2[4*i+1], an);
                an = fdot2u(hv.z, w2[4*i+2], an); an = fdot2u(hv.w, w2[4*i+3], an);
            }
            ar = qadd1(ar); az = qadd1(az); an = qadd1(an);
            const float r = fast_sigmoid(cr + ar);
            const float z = fast_sigmoid(cz + az);
            const float n = fast_tanh(cn + r * (an + bA));
            const float hnew = z * (hreg - n) + n;
            hreg = hnew;
            if (p == 0) {
                ((_Float16*)&hbufu[cur ^ 1][0])[j] = (_Float16)hnew;
                outbase[(size_t)tA * 256 + j] = hnew;
            }
            cur ^= 1;
        } else {
            const int rdA = tA + 6;                  // rows staged last group
            if (rdA < L_SEQ) {
                const unsigned int* xsA = &xstage[(g + 1) & 1][0][0];
                const unsigned int* xsB = &xstage[(g + 1) & 1][1][0];
                const int slA = rdA & (RING - 1), slB = (rdA + 1) & (RING - 1);
                ring[slA][u] = pdot32(w0, xsA, bA);
                ring[slB][u] = pdot32(w0, xsB, bA);
                if (u >= 128) {
                    ring[slA][128 + u] = pdot32(w1, xsA, bB);
                    ring[slB][128 + u] = pdot32(w1, xsB, bB);
                }
            }
            const int rl = tA + 8;                   // issue loads 8 ahead
            if (u < 64 && rl < L_SEQ) {
                const int rowIdx = rl + (u >= 32 ? 1 : 0);
                const int e = u & 31;
                const int srcL = isFwd ? rowIdx : (len - 1 - rowIdx);
                xv = make_float2(0.f, 0.f);
                if (srcL >= 0) xv = *(const float2*)&xseq[(size_t)srcL * C_IN + 2*e];
            }
        }
        STEP_BARRIER();
        // ========================= step B (t = 2g+1) =======================
        {
            const int tB = tA + 1;
            if (consumer) {
                const int sln = (tB + 1) & (RING - 1);       // prefetch t+2
                cr = ring[sln][j]; cz = ring[sln][128 + j]; cn = ring[sln][256 + j];
                float ar = 0.f, az = 0.f, an = 0.f;
                const uint4* hb = (const uint4*)&hbufu[cur][p * 32];
#pragma unroll
                for (int i = 0; i < 8; ++i) {
                    const uint4 hv = hb[i];
                    ar = fdot2u(hv.x, w0[4*i+0], ar); ar = fdot2u(hv.y, w0[4*i+1], ar);
                    ar = fdot2u(hv.z, w0[4*i+2], ar); ar = fdot2u(hv.w, w0[4*i+3], ar);
                    az = fdot2u(hv.x, w1[4*i+0], az); az = fdot2u(hv.y, w1[4*i+1], az);
                    az = fdot2u(hv.z, w1[4*i+2], az); az = fdot2u(hv.w, w1[4*i+3], az);
                    an = fdot2u(hv.x, w2[4*i+0], an); an = fdot2u(hv.y, w2[4*i+1], an);
                    an = fdot2u(hv.z, w2[4*i+2], an); an = fdot2u(hv.w, w2[4*i+3], an);
                }
                ar = qadd1(ar); az = qadd1(az); an = qadd1(an);
                const float r = fast_sigmoid(nr + ar);
                const float z = fast_sigmoid(nz + az);
                const float n = fast_tanh(nn + r * (an + bA));
                const float hnew = z * (hreg - n) + n;
                hreg = hnew;
                if (p == 0) {
                    ((_Float16*)&hbufu[cur ^ 1][0])[j] = (_Float16)hnew;
                    outbase[(size_t)tB * 256 + j] = hnew;
                }
                cur ^= 1;
            } else {
                if (u < 64 && tA + 8 < L_SEQ) {      // pack + stage loaded rows
                    xstage[g & 1][(u >= 32) ? 1 : 0][u & 31] = pack_h2(xv.x, xv.y);
                }
            }
        }
        STEP_BARRIER();
    }
}

// ---------------------------------------------------------------------------
extern "C" void kernel_launch(void* const* d_in, const int* in_sizes, int n_in,
                              void* d_out, int out_size, void* d_ws, size_t ws_size,
                              hipStream_t stream) {
    const float* x       = (const float*)d_in[0];
    const int*   lengths = (const int*)  d_in[1];
    const float* W_ih    = (const float*)d_in[2];
    const float* W_hh    = (const float*)d_in[3];
    const float* b_ih    = (const float*)d_in[4];
    const float* b_hh    = (const float*)d_in[5];
    float* out = (float*)d_out;

    // single fused launch: no global xw buffer, no chunking, d_ws unused
    bigru_fused<<<dim3(B2), dim3(512), 0, stream>>>(
        x, lengths, W_ih, W_hh, b_ih, b_hh, out);
}

// Round 10
// 1149.069 us; speedup vs baseline: 1.2842x; 1.0021x over previous
//
#include <hip/hip_runtime.h>

#define L_SEQ 2048
#define C_IN  64
#define HH    128
#define NSEQ  32
#define B2    64                   // 2*NSEQ sequences (fwd + rev)
#define G3    384                  // 3*H
#define RING  16                   // LDS xw ring slots (steps)
#define XW32  (C_IN / 2)           // 32 packed u32 per x row
#define XTOT  (NSEQ * L_SEQ * XW32)

typedef _Float16 half2_t __attribute__((ext_vector_type(2)));

// keep a value opaque + register-resident (defeats rematerialization)
#define PINU(v) asm volatile("" : "+v"(v))
// per-step barrier: drain LDS only; vmcnt (out-stores) stays in flight
#define STEP_BARRIER() asm volatile("s_waitcnt lgkmcnt(0)\n\ts_barrier" ::: "memory")

__device__ __forceinline__ float fdot2u(unsigned int a, unsigned int b, float c) {
    return __builtin_amdgcn_fdot2(__builtin_bit_cast(half2_t, a),
                                  __builtin_bit_cast(half2_t, b), c, false);
}

__device__ __forceinline__ unsigned int pack_h2(float a, float b) {
    half2_t t; t.x = (_Float16)a; t.y = (_Float16)b;   // RNE rounding
    return __builtin_bit_cast(unsigned int, t);
}

// quad-perm DPP add: reduce across lane^1, pure VALU (no DS pipe)
__device__ __forceinline__ float qadd1(float x) {
    int t = __builtin_amdgcn_update_dpp(0, __builtin_bit_cast(int, x),
                                        0xB1, 0xF, 0xF, true); // [1,0,3,2]
    return x + __builtin_bit_cast(float, t);
}

__device__ __forceinline__ float fast_sigmoid(float x) {
    float e = __builtin_amdgcn_exp2f(-1.4426950408889634f * x);
    return __builtin_amdgcn_rcpf(1.0f + e);
}

__device__ __forceinline__ float fast_tanh(float x) {
    float a = fabsf(x);
    float e = __builtin_amdgcn_exp2f(-2.8853900817779268f * a); // e^{-2a}
    float r = (1.0f - e) * __builtin_amdgcn_rcpf(1.0f + e);
    return copysignf(r, x);
}

// 32 x v_dot2 over one packed-f16 64-elem row; xrow is BLOCK-UNIFORM ->
// compiler emits s_load broadcast (SMEM pipe, zero DS / zero VMEM-per-lane).
__device__ __forceinline__ float pdot32(const unsigned int (&w)[32],
                                        const unsigned int* __restrict__ xrow,
                                        float acc) {
    const uint4* x4 = (const uint4*)xrow;
#pragma unroll
    for (int i = 0; i < 8; ++i) {
        const uint4 v = x4[i];
        acc = fdot2u(v.x, w[4*i+0], acc);
        acc = fdot2u(v.y, w[4*i+1], acc);
        acc = fdot2u(v.z, w[4*i+2], acc);
        acc = fdot2u(v.w, w[4*i+3], acc);
    }
    return acc;
}

// ---------------------------------------------------------------------------
// Pre-pass: pack x (f32) -> f16-pair rows in ws, plus one zero row at the end
// (used for the ragged-reverse tail). 8192 blocks x 256 threads, ~10 us.
// ---------------------------------------------------------------------------
__global__ __launch_bounds__(256)
void pack_x_kernel(const float* __restrict__ x, unsigned int* __restrict__ xh)
{
    const size_t i = (size_t)blockIdx.x * 256 + threadIdx.x;
    if (i < (size_t)XTOT) {
        const float2 v = ((const float2*)x)[i];
        xh[i] = pack_h2(v.x, v.y);
    }
    if (i < XW32) xh[(size_t)XTOT + i] = 0u;     // zero row
}

// ---------------------------------------------------------------------------
// Fused BiGRU: 64 blocks (one per sequence), 512 threads = 8 waves.
// Waves 0-3 (consumer): recurrence — col j = u>>1, K-half p = u&1, 96 packed
//   f16 W_hh pairs pinned in VGPRs, h f16 double-buffered in LDS, xw from the
//   LDS ring (1-step register prefetch).
// Waves 4-7 (producer): row t+6 of x@W_ih into the ring, ONE row per step
//   (rate-matched, no burst). x row fetched via block-uniform pointer ->
//   s_load broadcast: producer touches neither the DS-read pipe nor VMEM.
// Each SIMD hosts one consumer + one producer wave; producer issue fills the
// consumer's serial-latency window. One lgkmcnt-only barrier per step.
// ---------------------------------------------------------------------------
__global__ __launch_bounds__(512) __attribute__((amdgpu_waves_per_eu(1, 1)))
void bigru_fused(const unsigned int* __restrict__ xh,
                 const int* __restrict__ lengths,
                 const float* __restrict__ W_ih, const float* __restrict__ W_hh,
                 const float* __restrict__ b_ih, const float* __restrict__ b_hh,
                 float* __restrict__ out)
{
    __shared__ unsigned int hbufu[2][64];        // h as f16 pairs, double-buffered
    __shared__ float        ring[RING][G3];      // xw ring (biases folded)

    const int tid = threadIdx.x;
    const int s   = blockIdx.x;
    const bool isFwd = (s < NSEQ);
    const int  len   = isFwd ? L_SEQ : lengths[s - NSEQ];
    const unsigned int* __restrict__ xseq = xh + (size_t)(s % NSEQ) * L_SEQ * XW32;
    const unsigned int* __restrict__ zrow = xh + (size_t)XTOT;

    const bool consumer = (tid < 256);
    const int u = tid & 255;      // role-local thread id
    const int j = u >> 1;         // consumer: output column
    const int p = u & 1;          // consumer: K half

    // weight registers are UNIONED across roles (same virtual regs)
    unsigned int w0[32], w1[32], w2[32];
    float bA = 0.f, bB = 0.f;

    if (consumer) {
        const float* Wb = W_hh + (size_t)(64 * p) * G3;
#pragma unroll
        for (int k = 0; k < 32; ++k) {
            w0[k] = pack_h2(Wb[(2*k) * G3 + j],       Wb[(2*k+1) * G3 + j]);
            w1[k] = pack_h2(Wb[(2*k) * G3 + 128 + j], Wb[(2*k+1) * G3 + 128 + j]);
            w2[k] = pack_h2(Wb[(2*k) * G3 + 256 + j], Wb[(2*k+1) * G3 + 256 + j]);
        }
#pragma unroll
        for (int k = 0; k < 32; ++k) { PINU(w0[k]); PINU(w1[k]); PINU(w2[k]); }
        bA = b_hh[256 + j];                       // b_hh_n (used as r*(an+bA))
        if (tid < 64) hbufu[0][tid] = 0u;         // h0 = 0
    } else {
#pragma unroll
        for (int k = 0; k < 32; ++k)
            w0[k] = pack_h2(W_ih[(2*k) * G3 + u], W_ih[(2*k+1) * G3 + u]);
        bA = b_ih[u] + b_hh[u];                   // r/z cols: fold both biases
        if (u >= 128) {
            const int c1 = 128 + u;               // n-gate cols 256..383
#pragma unroll
            for (int k = 0; k < 32; ++k)
                w1[k] = pack_h2(W_ih[(2*k) * G3 + c1], W_ih[(2*k+1) * G3 + c1]);
            bB = b_ih[c1];
        }
#pragma unroll
        for (int k = 0; k < 32; ++k) { PINU(w0[k]); PINU(w1[k]); }

        // prologue: fill ring rows 0..5 (uniform s_load rows, no staging)
        for (int rd = 0; rd < 6; ++rd) {
            const int srcL = isFwd ? rd : (len - 1 - rd);
            const unsigned int* xrow =
                (srcL >= 0) ? (xseq + (size_t)srcL * XW32) : zrow;
            ring[rd][u] = pdot32(w0, xrow, bA);
            if (u >= 128) ring[rd][128 + u] = pdot32(w1, xrow, bB);
        }
    }
    __syncthreads();

    float cr = 0.f, cz = 0.f, cn = 0.f, hreg = 0.f;
    if (consumer) { cr = ring[0][j]; cz = ring[0][128 + j]; cn = ring[0][256 + j]; }

    float* outbase = out + (size_t)(s % NSEQ) * L_SEQ * 256 + (isFwd ? 0 : HH);
    int cur = 0;

    for (int t = 0; t < L_SEQ; ++t) {
        if (consumer) {
            const int sln = (t + 1) & (RING - 1);            // prefetch t+1
            const float nr = ring[sln][j];
            const float nz = ring[sln][128 + j];
            const float nn = ring[sln][256 + j];
            float ar = 0.f, az = 0.f, an = 0.f;
            const uint4* hb = (const uint4*)&hbufu[cur][p * 32];
#pragma unroll
            for (int i = 0; i < 8; ++i) {
                const uint4 hv = hb[i];
                ar = fdot2u(hv.x, w0[4*i+0], ar); ar = fdot2u(hv.y, w0[4*i+1], ar);
                ar = fdot2u(hv.z, w0[4*i+2], ar); ar = fdot2u(hv.w, w0[4*i+3], ar);
                az = fdot2u(hv.x, w1[4*i+0], az); az = fdot2u(hv.y, w1[4*i+1], az);
                az = fdot2u(hv.z, w1[4*i+2], az); az = fdot2u(hv.w, w1[4*i+3], az);
                an = fdot2u(hv.x, w2[4*i+0], an); an = fdot2u(hv.y, w2[4*i+1], an);
                an = fdot2u(hv.z, w2[4*i+2], an); an = fdot2u(hv.w, w2[4*i+3], an);
            }
            ar = qadd1(ar); az = qadd1(az); an = qadd1(an);
            const float r = fast_sigmoid(cr + ar);
            const float z = fast_sigmoid(cz + az);
            const float n = fast_tanh(cn + r * (an + bA));
            const float hnew = z * (hreg - n) + n;
            hreg = hnew;
            if (p == 0) {
                ((_Float16*)&hbufu[cur ^ 1][0])[j] = (_Float16)hnew;
                outbase[(size_t)t * 256 + j] = hnew;
            }
            cur ^= 1;
            cr = nr; cz = nz; cn = nn;
        } else {
            const int rd = t + 6;                // produce row t+6 (1 row/step)
            if (rd < L_SEQ) {
                const int srcL = isFwd ? rd : (len - 1 - rd);
                const unsigned int* xrow =
                    (srcL >= 0) ? (xseq + (size_t)srcL * XW32) : zrow;
                const int sl = rd & (RING - 1);
                ring[sl][u] = pdot32(w0, xrow, bA);
                if (u >= 128) ring[sl][128 + u] = pdot32(w1, xrow, bB);
            }
        }
        STEP_BARRIER();
    }
}

// ---------------------------------------------------------------------------
extern "C" void kernel_launch(void* const* d_in, const int* in_sizes, int n_in,
                              void* d_out, int out_size, void* d_ws, size_t ws_size,
                              hipStream_t stream) {
    const float* x       = (const float*)d_in[0];
    const int*   lengths = (const int*)  d_in[1];
    const float* W_ih    = (const float*)d_in[2];
    const float* W_hh    = (const float*)d_in[3];
    const float* b_ih    = (const float*)d_in[4];
    const float* b_hh    = (const float*)d_in[5];
    float* out = (float*)d_out;

    unsigned int* xh = (unsigned int*)d_ws;      // (XTOT + XW32) u32 = 8.4 MB

    pack_x_kernel<<<dim3((XTOT + 255) / 256), dim3(256), 0, stream>>>(x, xh);
    bigru_fused<<<dim3(B2), dim3(512), 0, stream>>>(
        xh, lengths, W_ih, W_hh, b_ih, b_hh, out);
}